// Round 8
// baseline (689.985 us; speedup 1.0000x reference)
//
#include <hip/hip_runtime.h>
#include <cstddef>

#define CC   128
#define LDIM 361
#define MDIM 361
#define KDIM 361
#define NLON 720
#define LP   384          // padded l (stage A K-dim)
#define KP   384          // padded k rows for pctT
#define KTP  384          // xsT row stride (k-contiguous)
#define MRP  736          // padded mr (stage B K-dim)
#define NP   768          // padded n (stage B N-dim)
#define CK   (CC*KDIM)    // 46208
#define CR   (2*CC)       // 256
#define CKT  722          // CK/64

typedef __attribute__((ext_vector_type(8))) short short8;
typedef __attribute__((ext_vector_type(4))) float floatx4;

__device__ __forceinline__ unsigned short f2bf(float f) {
    union { float f; unsigned u; } v; v.f = f;
    unsigned u = v.u;
    u += 0x7fffu + ((u >> 16) & 1u);   // RNE
    return (unsigned short)(u >> 16);
}

__device__ __forceinline__ void async_copy16(const void* g, void* l) {
    __builtin_amdgcn_global_load_lds(
        (const __attribute__((address_space(1))) void*)g,
        (__attribute__((address_space(3))) void*)l, 16, 0, 0);
}

// Bijective XCD-chunk swizzle (m204).
__device__ __forceinline__ int xcd_swz(int id, int P) {
    int x = id & 7, g = id >> 3;
    int q = P >> 3, r = P & 7;
    int start = (x < r) ? x * (q + 1) : r * (q + 1) + (x - r) * q;
    return start + g;
}

// ---------------------------------------------------------------------------
// Tp[n][mr] bf16, n<720 & mr<722 real weights, else 0 (pad kills xs poison).
__global__ void sht_gen_T(unsigned short* __restrict__ Tp) {
    int idx = blockIdx.x * 256 + threadIdx.x;
    if (idx >= NP * MRP) return;
    int n = idx / MRP, mr = idx - n * MRP;
    float v = 0.f;
    if (n < NLON && mr < 2 * MDIM) {
        int m = mr >> 1, im = mr & 1;
        if (m == 0)            v = im ? 0.f : 1.f;
        else if (m == MDIM-1)  v = im ? 0.f : ((n & 1) ? -1.f : 1.f);
        else {
            int ph = (m * n) % NLON;
            float ang = (float)ph * (float)(3.14159265358979323846 / 360.0);
            v = im ? (-2.f * sinf(ang)) : (2.f * cosf(ang));
        }
    }
    Tp[idx] = f2bf(v);
}

// ---------------------------------------------------------------------------
// x fp32 [c][l][m][r] -> xA bf16 [m][cr=2c+r][LP]  (round-6 plane version)
__global__ __launch_bounds__(256)
void sht_prep_x(const float* __restrict__ x, unsigned short* __restrict__ xA) {
    __shared__ float tp[2][32 * 65 + 4];
    const int mt = blockIdx.x;         // 0..11
    const int lt = blockIdx.y;         // 0..5
    const int c  = blockIdx.z;         // 0..127
    const int t  = threadIdx.x;

    #pragma unroll
    for (int u = 0; u < 8; ++u) {
        int p  = t + 256 * u;
        int li = p >> 5, mi = p & 31;
        int l = lt * 64 + li, m = mt * 32 + mi;
        float2 v = make_float2(0.f, 0.f);
        if (l < LDIM && m < MDIM)
            v = *(const float2*)(x + ((size_t)(c * LDIM + l) * MDIM + m) * 2);
        tp[0][mi * 65 + li] = v.x;
        tp[1][mi * 65 + li] = v.y;
    }
    __syncthreads();

    #pragma unroll
    for (int u = 0; u < 2; ++u) {
        int s  = t + 256 * u;          // 0..511
        int mi = s >> 4, rr = (s >> 3) & 1, lo = (s & 7) * 8;
        int m = mt * 32 + mi;
        if (m >= MDIM) continue;
        const float* pl = &tp[rr][mi * 65];
        short8 h;
        #pragma unroll
        for (int e = 0; e < 8; ++e)
            h[e] = (short)f2bf(pl[lo + e]);
        *(short8*)(xA + ((size_t)m * CR + 2 * c + rr) * LP + lt * 64 + lo) = h;
    }
}

// ---------------------------------------------------------------------------
// pct fp32 [m][l][k] -> pctT bf16 [m][k][LP] v2: 64lx64k tiles.
__global__ __launch_bounds__(256)
void sht_prep_pct(const float* __restrict__ pct, unsigned short* __restrict__ pctT) {
    __shared__ float tile[64][65];     // 16.6 KB
    const int m  = blockIdx.y;
    const int bx = blockIdx.x;         // 0..35
    const int kt = bx % 6, lt = bx / 6;
    const int l0 = lt * 64, k0 = kt * 64;
    const int t  = threadIdx.x;

    const int ki = t & 63, lb = t >> 6;    // 4 l-rows per pass
    #pragma unroll
    for (int u = 0; u < 16; ++u) {
        int li = lb + 4 * u;
        int l = l0 + li, k = k0 + ki;
        float v = 0.f;
        if (l < LDIM && k < KDIM)
            v = pct[((size_t)m * LDIM + l) * KDIM + k];
        tile[li][ki] = v;
    }
    __syncthreads();

    #pragma unroll
    for (int u = 0; u < 2; ++u) {
        int s = t + 256 * u;               // 0..511
        int ko = s >> 3, lo = (s & 7) * 8; // 64 k-rows x 8 l-octets
        short8 h;
        #pragma unroll
        for (int e = 0; e < 8; ++e)
            h[e] = (short)f2bf(tile[lo + e][ko]);
        *(short8*)(pctT + ((size_t)m * KP + k0 + ko) * LP + l0 + lo) = h;
    }
}

// ---------------------------------------------------------------------------
// Stage A7: BM=64 x BN=384, 256 thr, 2-buffer ring (56KB LDS -> 2 blocks/CU).
// Schedule: stage(it+1) -> vmcnt(7) -> bar -> ds_read -> lgkm(0) -> bar -> MFMA.
// Cross-block overlap (2 blocks/CU) hides the per-iter barrier/latency stalls
// that dominated the 512-thr 1-block/CU versions.
__global__ __launch_bounds__(256)
void sht_stageA7(const unsigned short* __restrict__ pctT, const unsigned short* __restrict__ xA,
                 unsigned short* __restrict__ xsT) {
    __shared__ unsigned short As[2][64 * 32];    // 2 x 4 KB
    __shared__ unsigned short Bs[2][384 * 32];   // 2 x 24 KB

    const int p   = xcd_swz(blockIdx.x, 4 * MDIM);
    const int m   = p >> 2, ct = p & 3;
    const int c0  = ct * 64;
    const int t   = threadIdx.x;
    const int w   = t >> 6, L = t & 63;
    const int wc  = w;                            // 4 N-quarters, 1 M-row
    const int lane15 = L & 15, quad = L >> 4;
    const int arr = t >> 2, alq = (t & 3) ^ (arr & 3);

    const unsigned short* xAm = xA + (size_t)m * CR * LP;
    const unsigned short* pTm = pctT + (size_t)m * KP * LP;

    floatx4 acc[4][6] = {};

    auto stage = [&](int buf, int kb) {
        async_copy16(xAm + (size_t)(c0 + arr) * LP + kb + alq * 8,
                     &As[buf][(w * 64) * 8]);
        #pragma unroll
        for (int u = 0; u < 6; ++u) {
            int s = u * 256 + t;
            int rr = s >> 2, lq = (s & 3) ^ (rr & 3);
            async_copy16(pTm + (size_t)rr * LP + kb + lq * 8,
                         &Bs[buf][(u * 256 + w * 64) * 8]);
        }
    };

    const int NT = LP / 32;    // 12
    stage(0, 0);

    for (int it = 0; it < NT; ++it) {
        const int cur = it & 1;
        if (it + 1 < NT) {
            stage(cur ^ 1, (it + 1) * 32);
            asm volatile("s_waitcnt vmcnt(7)" ::: "memory");
        } else {
            asm volatile("s_waitcnt vmcnt(0)" ::: "memory");
        }
        __builtin_amdgcn_sched_barrier(0);
        __builtin_amdgcn_s_barrier();
        __builtin_amdgcn_sched_barrier(0);

        short8 af[4], bf[6];
        #pragma unroll
        for (int i = 0; i < 4; ++i) {
            int row = i * 16 + lane15;
            af[i] = *(const short8*)&As[cur][(row * 4 + (quad ^ (row & 3))) * 8];
        }
        #pragma unroll
        for (int j = 0; j < 6; ++j) {
            int row = wc * 96 + j * 16 + lane15;
            bf[j] = *(const short8*)&Bs[cur][(row * 4 + (quad ^ (row & 3))) * 8];
        }
        asm volatile("s_waitcnt lgkmcnt(0)" ::: "memory");
        __builtin_amdgcn_sched_barrier(0);
        __builtin_amdgcn_s_barrier();
        __builtin_amdgcn_sched_barrier(0);

        __builtin_amdgcn_s_setprio(1);
        #pragma unroll
        for (int i = 0; i < 4; ++i)
            #pragma unroll
            for (int j = 0; j < 6; ++j)
                acc[i][j] = __builtin_amdgcn_mfma_f32_16x16x32_bf16(af[i], bf[j], acc[i][j], 0, 0, 0);
        __builtin_amdgcn_s_setprio(0);
    }

    // coalesced: lane15 -> consecutive k; 16-lane group = 32B contiguous
    #pragma unroll
    for (int i = 0; i < 4; ++i) {
        #pragma unroll
        for (int j = 0; j < 6; ++j) {
            int k = wc * 96 + j * 16 + lane15;
            #pragma unroll
            for (int e = 0; e < 4; ++e) {
                int cr = c0 + i * 16 + quad * 4 + e;
                xsT[((size_t)m * CR + cr) * KTP + k] = f2bf(acc[i][j][e]);
            }
        }
    }
}

// ---------------------------------------------------------------------------
// xsT bf16 [m][cr][KTP] -> xs bf16 [ck][MRP]; u32-pack transpose, <=2-way banks.
__global__ __launch_bounds__(256)
void sht_xs_tr(const unsigned short* __restrict__ xsT, unsigned short* __restrict__ xs) {
    __shared__ unsigned tile32[64 * 65];   // [k][mi] u32 = (bf16 r0 | r1<<16)
    const int c  = blockIdx.y;          // 0..127
    const int bx = blockIdx.x;          // 0..35
    const int mt = bx / 6, kt = bx % 6;
    const int m0 = mt * 64, k0 = kt * 64;
    const int t  = threadIdx.x;

    #pragma unroll
    for (int u = 0; u < 2; ++u) {
        int q  = t + 256 * u;
        int mi = q >> 3, ko8 = q & 7;
        int m  = m0 + mi;
        short8 a = {}, b = {};
        if (m < MDIM) {
            const unsigned short* base = xsT + ((size_t)m * CR + 2 * c) * KTP + k0 + ko8 * 8;
            a = *(const short8*)base;
            b = *(const short8*)(base + KTP);
        }
        #pragma unroll
        for (int e = 0; e < 8; ++e)
            tile32[(ko8 * 8 + e) * 65 + mi] =
                (unsigned)(unsigned short)a[e] | ((unsigned)(unsigned short)b[e] << 16);
    }
    __syncthreads();

    #pragma unroll
    for (int u = 0; u < 4; ++u) {
        int q  = t + 256 * u;
        int kk = q >> 4, mc = q & 15;
        int k  = k0 + kk;
        int mr0 = 2 * m0 + mc * 8;
        if (k >= KDIM || mr0 >= MRP) continue;
        unsigned w0 = tile32[kk * 65 + mc * 4 + 0];
        unsigned w1 = tile32[kk * 65 + mc * 4 + 1];
        unsigned w2 = tile32[kk * 65 + mc * 4 + 2];
        unsigned w3 = tile32[kk * 65 + mc * 4 + 3];
        unsigned* dst = (unsigned*)(xs + (size_t)(c * KDIM + k) * MRP + mr0);
        dst[0] = w0; dst[1] = w1; dst[2] = w2; dst[3] = w3;
    }
}

// ---------------------------------------------------------------------------
// Stage A2 (fast1 fallback): scatter epilogue direct to xs (round-3, 148us).
__global__ __launch_bounds__(512)
void sht_stageA2(const unsigned short* __restrict__ pctT, const unsigned short* __restrict__ xA,
                 unsigned short* __restrict__ xs) {
    __shared__ unsigned short As[128 * 32];
    __shared__ unsigned short Bs[384 * 32];

    const int p   = xcd_swz(blockIdx.x, 2 * MDIM);
    const int m   = p >> 1, ct = p & 1;
    const int c0  = ct * 128;
    const int t   = threadIdx.x;
    const int w   = t >> 6, L = t & 63;
    const int wr  = w & 1, wc = w >> 1;
    const int lane15 = L & 15, quad = L >> 4;
    const int arr = t >> 2, alq = t & 3;

    const unsigned short* xAm = xA + (size_t)m * CR * LP;
    const unsigned short* pTm = pctT + (size_t)m * KP * LP;

    floatx4 acc[4][6] = {};

    for (int kb = 0; kb < LP; kb += 32) {
        async_copy16(xAm + (size_t)(c0 + arr) * LP + kb + alq * 8,
                     As + (size_t)(w * 64) * 8);
        #pragma unroll
        for (int u = 0; u < 3; ++u) {
            int s = u * 512 + t;
            int rr = s >> 2, lq = s & 3;
            async_copy16(pTm + (size_t)rr * LP + kb + lq * 8,
                         Bs + (size_t)(u * 512 + w * 64) * 8);
        }
        __syncthreads();

        short8 af[4], bf[6];
        #pragma unroll
        for (int i = 0; i < 4; ++i)
            af[i] = *(const short8*)&As[((wr * 64 + i * 16 + lane15) * 4 + quad) * 8];
        #pragma unroll
        for (int j = 0; j < 6; ++j)
            bf[j] = *(const short8*)&Bs[((wc * 96 + j * 16 + lane15) * 4 + quad) * 8];
        #pragma unroll
        for (int i = 0; i < 4; ++i)
            #pragma unroll
            for (int j = 0; j < 6; ++j)
                acc[i][j] = __builtin_amdgcn_mfma_f32_16x16x32_bf16(af[i], bf[j], acc[i][j], 0, 0, 0);
        __syncthreads();
    }

    #pragma unroll
    for (int j = 0; j < 6; ++j) {
        int k = wc * 96 + j * 16 + lane15;
        if (k >= KDIM) continue;
        #pragma unroll
        for (int i = 0; i < 4; ++i) {
            #pragma unroll
            for (int eh = 0; eh < 2; ++eh) {
                int cr = c0 + wr * 64 + i * 16 + quad * 4 + eh * 2;
                int c  = cr >> 1;
                unsigned pack = (unsigned)f2bf(acc[i][j][eh * 2]) |
                                ((unsigned)f2bf(acc[i][j][eh * 2 + 1]) << 16);
                *(unsigned*)(xs + (size_t)(c * KDIM + k) * MRP + 2 * m) = pack;
            }
        }
    }
}

// ---------------------------------------------------------------------------
// Stage A (tier0 fallback): original in-loop fp32 pct staging.
__global__ __launch_bounds__(256)
void sht_stageA(const float* __restrict__ pct, const unsigned short* __restrict__ xA,
                unsigned short* __restrict__ xs) {
    __shared__ unsigned short As[128 * 32];
    __shared__ unsigned short Bs[32 * 130];

    const int m   = blockIdx.y;
    const int ct  = blockIdx.x & 1;
    const int kt  = blockIdx.x >> 1;
    const int c0  = ct * 128;
    const int n0  = kt * 128;
    const int t   = threadIdx.x;
    const int w   = t >> 6, L = t & 63;
    const int wr  = w & 1, wc = w >> 1;
    const int lane15 = L & 15, quad = L >> 4;
    const int bl = t >> 3, bkq = t & 7;

    const unsigned short* xAm = xA + (size_t)m * CR * LP;
    const float* pctm = pct + (size_t)m * LDIM * KDIM;

    floatx4 acc[4][4] = {};

    for (int kb = 0; kb < LP; kb += 32) {
        #pragma unroll
        for (int i = 0; i < 2; ++i) {
            int s = w * 128 + i * 64 + L;
            int cr = s >> 2, lq = s & 3;
            async_copy16(xAm + (size_t)(c0 + cr) * LP + kb + lq * 8,
                         As + (size_t)(w * 128 + i * 64) * 8);
        }
        {
            int l = kb + bl;
            bool lok = (l < LDIM);
            const float* prow = pctm + (size_t)l * KDIM;
            #pragma unroll
            for (int u = 0; u < 4; ++u) {
                int kc = n0 + u * 32 + bkq * 4;
                float f0 = (lok && kc + 0 < KDIM) ? prow[kc + 0] : 0.f;
                float f1 = (lok && kc + 1 < KDIM) ? prow[kc + 1] : 0.f;
                float f2 = (lok && kc + 2 < KDIM) ? prow[kc + 2] : 0.f;
                float f3 = (lok && kc + 3 < KDIM) ? prow[kc + 3] : 0.f;
                unsigned* bp = (unsigned*)&Bs[bl * 130 + u * 32 + bkq * 4];
                bp[0] = (unsigned)f2bf(f0) | ((unsigned)f2bf(f1) << 16);
                bp[1] = (unsigned)f2bf(f2) | ((unsigned)f2bf(f3) << 16);
            }
        }
        __syncthreads();

        short8 af[4];
        #pragma unroll
        for (int i = 0; i < 4; ++i) {
            int row = wr * 64 + i * 16 + lane15;
            af[i] = *(const short8*)&As[(row * 4 + quad) * 8];
        }
        #pragma unroll
        for (int jf = 0; jf < 4; ++jf) {
            int col = wc * 64 + jf * 16 + lane15;
            short8 bf;
            #pragma unroll
            for (int j = 0; j < 8; ++j)
                bf[j] = (short)Bs[(quad * 8 + j) * 130 + col];
            #pragma unroll
            for (int i = 0; i < 4; ++i)
                acc[i][jf] = __builtin_amdgcn_mfma_f32_16x16x32_bf16(af[i], bf, acc[i][jf], 0, 0, 0);
        }
        __syncthreads();
    }

    #pragma unroll
    for (int i = 0; i < 4; ++i) {
        #pragma unroll
        for (int jf = 0; jf < 4; ++jf) {
            int k = n0 + wc * 64 + jf * 16 + lane15;
            if (k >= KDIM) continue;
            #pragma unroll
            for (int eh = 0; eh < 2; ++eh) {
                int cr = c0 + wr * 64 + i * 16 + quad * 4 + eh * 2;
                int c  = cr >> 1;
                unsigned pack = (unsigned)f2bf(acc[i][jf][eh * 2]) |
                                ((unsigned)f2bf(acc[i][jf][eh * 2 + 1]) << 16);
                *(unsigned*)(xs + (size_t)(c * KDIM + k) * MRP + 2 * m) = pack;
            }
        }
    }
}

// ---------------------------------------------------------------------------
// Stage B6: BM=64 x BN=384, 256 thr, 2-buffer ring (56KB -> 2 blocks/CU).
__global__ __launch_bounds__(256)
void sht_stageB6(const unsigned short* __restrict__ xs, const unsigned short* __restrict__ Tp,
                 float* __restrict__ out) {
    __shared__ unsigned short As[2][64 * 32];    // 2 x 4 KB
    __shared__ unsigned short Bs[2][384 * 32];   // 2 x 24 KB

    const int p   = xcd_swz(blockIdx.x, 2 * CKT);
    const int ckt = p >> 1, nt = p & 1;
    const int ck0 = ckt * 64, n0 = nt * 384;
    const int t   = threadIdx.x;
    const int w   = t >> 6, L = t & 63;
    const int wc  = w;
    const int lane15 = L & 15, quad = L >> 4;
    const int arr = t >> 2, alq = (t & 3) ^ (arr & 3);

    floatx4 acc[4][6] = {};

    auto stage = [&](int buf, int kb) {
        async_copy16(xs + (size_t)(ck0 + arr) * MRP + kb + alq * 8,
                     &As[buf][(w * 64) * 8]);
        #pragma unroll
        for (int u = 0; u < 6; ++u) {
            int s = u * 256 + t;
            int rr = s >> 2, lq = (s & 3) ^ (rr & 3);
            async_copy16(Tp + (size_t)(n0 + rr) * MRP + kb + lq * 8,
                         &Bs[buf][(u * 256 + w * 64) * 8]);
        }
    };

    const int NT = MRP / 32;   // 23
    stage(0, 0);

    for (int it = 0; it < NT; ++it) {
        const int cur = it & 1;
        if (it + 1 < NT) {
            stage(cur ^ 1, (it + 1) * 32);
            asm volatile("s_waitcnt vmcnt(7)" ::: "memory");
        } else {
            asm volatile("s_waitcnt vmcnt(0)" ::: "memory");
        }
        __builtin_amdgcn_sched_barrier(0);
        __builtin_amdgcn_s_barrier();
        __builtin_amdgcn_sched_barrier(0);

        short8 af[4], bf[6];
        #pragma unroll
        for (int i = 0; i < 4; ++i) {
            int row = i * 16 + lane15;
            af[i] = *(const short8*)&As[cur][(row * 4 + (quad ^ (row & 3))) * 8];
        }
        #pragma unroll
        for (int j = 0; j < 6; ++j) {
            int row = wc * 96 + j * 16 + lane15;
            bf[j] = *(const short8*)&Bs[cur][(row * 4 + (quad ^ (row & 3))) * 8];
        }
        asm volatile("s_waitcnt lgkmcnt(0)" ::: "memory");
        __builtin_amdgcn_sched_barrier(0);
        __builtin_amdgcn_s_barrier();
        __builtin_amdgcn_sched_barrier(0);

        __builtin_amdgcn_s_setprio(1);
        #pragma unroll
        for (int i = 0; i < 4; ++i)
            #pragma unroll
            for (int j = 0; j < 6; ++j)
                acc[i][j] = __builtin_amdgcn_mfma_f32_16x16x32_bf16(af[i], bf[j], acc[i][j], 0, 0, 0);
        __builtin_amdgcn_s_setprio(0);
    }

    #pragma unroll
    for (int i = 0; i < 4; ++i) {
        int ckr = ck0 + i * 16 + quad * 4;
        #pragma unroll
        for (int j = 0; j < 6; ++j) {
            int jj = n0 + wc * 96 + j * 16 + lane15;
            if (jj >= NLON) continue;
            #pragma unroll
            for (int e = 0; e < 4; ++e)
                out[(size_t)(ckr + e) * NLON + jj] = acc[i][j][e];
        }
    }
}

// ---------------------------------------------------------------------------
extern "C" void kernel_launch(void* const* d_in, const int* in_sizes, int n_in,
                              void* d_out, int out_size, void* d_ws, size_t ws_size,
                              hipStream_t stream) {
    const float* x   = (const float*)d_in[0];   // [1,128,361,361,2] fp32
    const float* pct = (const float*)d_in[1];   // [361,361,361] fp32
    float* out = (float*)d_out;                 // [1,128,361,720] fp32

    unsigned short* xs = (unsigned short*)d_ws;              // CK*MRP (68.0 MB)
    unsigned short* Tp = xs + (size_t)CK * MRP;              // NP*MRP (1.13 MB)
    unsigned short* xA = (unsigned short*)d_out;             // dead before stage B

    const size_t base_shorts = (size_t)CK * MRP + (size_t)NP * MRP;
    const size_t pctT_shorts = (size_t)MDIM * KP * LP;       // 106.5 MB
    const size_t xsT_shorts  = (size_t)MDIM * CR * KTP;      // 71.0 MB
    const bool fast1 = ws_size >= (base_shorts + pctT_shorts) * sizeof(unsigned short);
    const bool fast2 = ws_size >= (base_shorts + pctT_shorts + xsT_shorts) * sizeof(unsigned short);

    sht_gen_T<<<(NP * MRP + 255) / 256, 256, 0, stream>>>(Tp);
    sht_prep_x<<<dim3(12, 6, 128), 256, 0, stream>>>(x, xA);
    if (fast2) {
        unsigned short* pctT = Tp + (size_t)NP * MRP;
        unsigned short* xsT  = pctT + pctT_shorts;
        sht_prep_pct<<<dim3(36, MDIM), 256, 0, stream>>>(pct, pctT);
        sht_stageA7<<<dim3(4 * MDIM), 256, 0, stream>>>(pctT, xA, xsT);
        sht_xs_tr<<<dim3(36, 128), 256, 0, stream>>>(xsT, xs);
    } else if (fast1) {
        unsigned short* pctT = Tp + (size_t)NP * MRP;
        sht_prep_pct<<<dim3(36, MDIM), 256, 0, stream>>>(pct, pctT);
        sht_stageA2<<<dim3(2 * MDIM), 512, 0, stream>>>(pctT, xA, xs);
    } else {
        sht_stageA<<<dim3(6, MDIM), 256, 0, stream>>>(pct, xA, xs);
    }
    sht_stageB6<<<dim3(2 * CKT), 256, 0, stream>>>(xs, Tp, out);
}